// Round 5
// baseline (360.012 us; speedup 1.0000x reference)
//
#include <hip/hip_runtime.h>

// Quantize/dequantize with 64-level sorted codebook (L=64).
//   r = x - means
//   pos = clip(searchsorted(cb, r), 1, 63)           // side='left'
//   sym = (r - cb[pos-1] <= cb[pos] - r) ? pos-1 : pos
//   y_hat = cb[sym] + means
// FP ops replicate the JAX reference exactly -> absmax 0.
//
// R5 design (R3/R4 were latency-bound: dependent per-element LDS/bpermute
// chains, compiler serialized at VGPR=24):
//  - tree steps s=32,16,8,4 in registers from 15 wave-uniform codebook values
//    (s_load'ed SGPRs) -> p4 = lower_bound & ~3, 16B-aligned.
//  - remaining: cb[p4..p4+3] via ONE aligned ds_read_b128 + cb[p4-1] via one
//    ds_read_b32; the two are independent. lb = p4 + sum(cb[p4+k] < r),
//    pos = clip(lb,1,63), left/right selected from the 5 regs. Chain depth 1.
//  - phases: 4 global loads -> 8 reg-only trees -> 16 LDS reads batched
//    (single wait) -> 8 resolves -> 4 nt stores. LDS latency paid once.
//  - contiguous float4 pair per thread (2t, 2t+1): 4 streams, not 8.

typedef float v4f __attribute__((ext_vector_type(4)));

struct Tree {
    float c31;
    float c15, c47;
    float c07, c23, c39, c55;
    float c03, c11, c19, c27, c35, c43, c51, c59;
};

__device__ __forceinline__ int tree4(const Tree& t, float r)
{
    // 4 MSB steps of lower_bound: returns (#{j: cb[j] < r}) & ~3  (or 60 if lb=64)
    int p = (t.c31 < r) ? 32 : 0;

    float v = (p & 32) ? t.c47 : t.c15;
    p += (v < r) ? 16 : 0;

    float u0 = (p & 16) ? t.c23 : t.c07;
    float u1 = (p & 16) ? t.c55 : t.c39;
    v = (p & 32) ? u1 : u0;
    p += (v < r) ? 8 : 0;

    float w0 = (p & 8) ? t.c11 : t.c03;
    float w1 = (p & 8) ? t.c27 : t.c19;
    float w2 = (p & 8) ? t.c43 : t.c35;
    float w3 = (p & 8) ? t.c59 : t.c51;
    float w4 = (p & 16) ? w1 : w0;
    float w5 = (p & 16) ? w3 : w2;
    v = (p & 32) ? w5 : w4;
    p += (v < r) ? 4 : 0;
    return p;
}

__global__ __launch_bounds__(256, 4) void quant_dequant_kernel(
    const v4f* __restrict__ x4,
    const v4f* __restrict__ m4,
    const float* __restrict__ codebook,
    v4f* __restrict__ sym_out,   // symbols as float values
    v4f* __restrict__ yhat_out,
    int n4)
{
    __shared__ __align__(16) float s_cb[64];
    const int tid = threadIdx.x;
    if (tid < 64) s_cb[tid] = codebook[tid];

    Tree t;   // wave-uniform: compiler emits s_load into SGPRs
    t.c31 = codebook[31];
    t.c15 = codebook[15]; t.c47 = codebook[47];
    t.c07 = codebook[7];  t.c23 = codebook[23];
    t.c39 = codebook[39]; t.c55 = codebook[55];
    t.c03 = codebook[3];  t.c11 = codebook[11];
    t.c19 = codebook[19]; t.c27 = codebook[27];
    t.c35 = codebook[35]; t.c43 = codebook[43];
    t.c51 = codebook[51]; t.c59 = codebook[59];

    __syncthreads();

    const int i = (blockIdx.x * 256 + tid) * 2;   // contiguous pair of float4s
    if (i >= n4) return;

    // phase 0: all global loads up front
    const v4f xa = x4[i];
    const v4f ma = m4[i];
    const v4f xb = x4[i + 1];
    const v4f mb = m4[i + 1];

    float r[8], mm[8];
#pragma unroll
    for (int k = 0; k < 4; ++k) {
        r[k]     = xa[k] - ma[k];  mm[k]     = ma[k];
        r[4 + k] = xb[k] - mb[k];  mm[4 + k] = mb[k];
    }

    // phase 1: register-only trees (no memory)
    int p4[8];
#pragma unroll
    for (int e = 0; e < 8; ++e) p4[e] = tree4(t, r[e]);

    // phase 2: all LDS reads, independent, one wait
    v4f  q[8];
    float vm1[8];
#pragma unroll
    for (int e = 0; e < 8; ++e) {
        q[e]   = *(const v4f*)&s_cb[p4[e]];        // ds_read_b128, 16B-aligned
        vm1[e] = s_cb[max(p4[e] - 1, 0)];          // ds_read_b32 (unused if p4==0)
    }

    // phase 3: resolve
    float sym[8], yv[8];
#pragma unroll
    for (int e = 0; e < 8; ++e) {
        const v4f qq = q[e];
        const float rr = r[e];
        const int lb = p4[e] + ((qq[0] < rr) ? 1 : 0) + ((qq[1] < rr) ? 1 : 0)
                             + ((qq[2] < rr) ? 1 : 0) + ((qq[3] < rr) ? 1 : 0);
        const int pos = min(max(lb, 1), 63);
        const int tt  = pos - p4[e];               // 0..3; 0 only possible when p4>0
        const float left  = (tt == 1) ? qq[0] : (tt == 2) ? qq[1]
                          : (tt == 3) ? qq[2] : vm1[e];
        const float right = (tt == 1) ? qq[1] : (tt == 2) ? qq[2]
                          : (tt == 3) ? qq[3] : qq[0];
        const bool tie = (rr - left) <= (right - rr);
        sym[e] = (float)(tie ? pos - 1 : pos);
        yv[e]  = (tie ? left : right) + mm[e];
    }

    const v4f sa = { sym[0], sym[1], sym[2], sym[3] };
    const v4f sb = { sym[4], sym[5], sym[6], sym[7] };
    const v4f ya = { yv[0],  yv[1],  yv[2],  yv[3]  };
    const v4f yb = { yv[4],  yv[5],  yv[6],  yv[7]  };

    __builtin_nontemporal_store(sa, &sym_out[i]);
    __builtin_nontemporal_store(sb, &sym_out[i + 1]);
    __builtin_nontemporal_store(ya, &yhat_out[i]);
    __builtin_nontemporal_store(yb, &yhat_out[i + 1]);
}

extern "C" void kernel_launch(void* const* d_in, const int* in_sizes, int n_in,
                              void* d_out, int out_size, void* d_ws, size_t ws_size,
                              hipStream_t stream)
{
    const float* x     = (const float*)d_in[0];
    const float* means = (const float*)d_in[1];
    const float* cb    = (const float*)d_in[2];

    const int n  = in_sizes[0];      // 25,165,824
    const int n4 = n / 4;            // 6,291,456

    float* out = (float*)d_out;      // [0..n): symbols (as float), [n..2n): y_hat

    const int block = 256;
    const int f4_per_block = block * 2;                       // 512
    const int grid = (n4 + f4_per_block - 1) / f4_per_block;  // 12288

    quant_dequant_kernel<<<grid, block, 0, stream>>>(
        (const v4f*)x, (const v4f*)means, cb,
        (v4f*)out, (v4f*)(out + n), n4);
}